// Round 2
// baseline (155.064 us; speedup 1.0000x reference)
//
#include <hip/hip_runtime.h>
#include <stdint.h>

#define NROWS 8192
#define DD 128
#define EPS 1e-8f
#define LOG2E 1.4426950408889634f

// symmetric-triangle main kernel tiling
#define TB 128                            // tile edge (rows == cols)
#define NTILE (NROWS / TB)                // 64 tile-rows
#define NPAIRS (NTILE * (NTILE + 1) / 2)  // 2080 upper-triangle tiles
#define LDS_COL 272    // bytes per staged col (256+16 pad -> 2-way max on quarter-wave, free)
#define NORM_BLOCKS (NROWS / 4)
#define PACK_BLOCKS 3200   // 100 classes * 128 u64-words / 4 waves

typedef __bf16 bf16x8 __attribute__((ext_vector_type(8)));
typedef float f32x4 __attribute__((ext_vector_type(4)));

__device__ __forceinline__ unsigned int f2bf(float f) {
  union { float f; unsigned int u; } v; v.f = f;
  unsigned int u = v.u;
  return (u + 0x7fffu + ((u >> 16) & 1u)) >> 16;
}
__device__ __forceinline__ float bf2f(unsigned int b) {
  union { unsigned int u; float f; } v; v.u = b << 16;
  return v.f;
}

// Kernel 1 (blocks < NORM_BLOCKS): per-row normalize.
//   xnA = bf16(x/||x|| * log2e/T)  (A operand pre-scaled: e = exp2(acc))
//   xnB = bf16(x/||x||)            (B operand)
//   p = exp2(cos(x,proxy)*log2e/T)  [margin cancels in num/den ratio]
//   e_self = exp2(<xnA_bf16, xnB_bf16>)  (MFMA diagonal, subtracted in loss)
//   mii = negmask[label_i][i]; zero tot/msk/out.
// Kernel 1 (blocks >= NORM_BLOCKS): ballot-pack negmask into u32 bit-words:
//   packed[class*256 + j/32] bit (j&31) = (negmask[class][j] != 0)
__global__ __launch_bounds__(256) void norm_kernel(
    const float* __restrict__ x, const float* __restrict__ pr,
    const float* __restrict__ nm, const int* __restrict__ lb,
    const float* __restrict__ tptr,
    unsigned short* __restrict__ xnA, unsigned short* __restrict__ xnB,
    float* __restrict__ p, float* __restrict__ eself, float* __restrict__ mii,
    float* __restrict__ tot, float* __restrict__ msk,
    unsigned int* __restrict__ packed, float* __restrict__ out)
{
  int wave = threadIdx.x >> 6, lane = threadIdx.x & 63;
  int bx = blockIdx.x;

  if (bx >= NORM_BLOCKS) {
    // ---- mask pack branch ----
    int widx = (bx - NORM_BLOCKS) * 4 + wave;   // 0..12799
    int cls = widx >> 7;                        // 0..99
    int w64 = widx & 127;                       // u64-word within class
    float v = nm[(size_t)cls * NROWS + w64 * 64 + lane];
    unsigned long long b = __ballot(v != 0.0f);
    if (lane == 0) {
      packed[cls * 256 + w64 * 2] = (unsigned int)b;
      packed[cls * 256 + w64 * 2 + 1] = (unsigned int)(b >> 32);
    }
    return;
  }

  int row = bx * 4 + wave;
  float2 xv = ((const float2*)(x + (size_t)row * DD))[lane];
  float2 pv = ((const float2*)(pr + (size_t)row * DD))[lane];
  float sx = xv.x * xv.x + xv.y * xv.y;
  float sp = pv.x * pv.x + pv.y * pv.y;
  float dp = xv.x * pv.x + xv.y * pv.y;
  #pragma unroll
  for (int m = 1; m < 64; m <<= 1) {
    sx += __shfl_xor(sx, m);
    sp += __shfl_xor(sp, m);
    dp += __shfl_xor(dp, m);
  }
  float inx = 1.f / fmaxf(sqrtf(sx), EPS);
  float inp = 1.f / fmaxf(sqrtf(sp), EPS);
  float s1 = LOG2E / tptr[0];

  unsigned int a0 = f2bf(xv.x * inx * s1), a1 = f2bf(xv.y * inx * s1);
  unsigned int b0 = f2bf(xv.x * inx),      b1 = f2bf(xv.y * inx);
  ((unsigned int*)(xnA + (size_t)row * DD))[lane] = a0 | (a1 << 16);
  ((unsigned int*)(xnB + (size_t)row * DD))[lane] = b0 | (b1 << 16);

  // self-sim with the SAME rounded values the MFMA will see
  float ss = bf2f(a0) * bf2f(b0) + bf2f(a1) * bf2f(b1);
  #pragma unroll
  for (int m = 1; m < 64; m <<= 1) ss += __shfl_xor(ss, m);

  if (lane == 0) {
    p[row] = __builtin_amdgcn_exp2f(dp * inx * inp * s1);
    eself[row] = __builtin_amdgcn_exp2f(ss);
    mii[row] = nm[(size_t)lb[row] * NROWS + row];
    tot[row] = 0.f;
    msk[row] = 0.f;
    if (row == 0) out[0] = 0.f;
  }
}

// Kernel 2 (symmetric): one block per upper-triangle 128x128 tile (ri<=cj).
// e_ij = e_ji, so each off-diagonal tile contributes BOTH row-sums (rows RI,
// reduce over c-lanes) and col-sums (rows CJ, reduce over q-lanes). Diagonal
// tiles contribute row-sums only. This halves MFMA/LDS/exp work device-wide.
// 4 waves in a 2x2 grid: wave (wm,wn) owns rows wm*64..+63 x cols wn*64..+63;
// each B fragment feeds 4 row-strips (4x LDS reuse). K=128 entirely in
// registers -> ONE barrier per block (after B staging), no K-loop.
__global__ __launch_bounds__(256, 2) void main_kernel(
    const unsigned short* __restrict__ xnA_u, const unsigned short* __restrict__ xnB_u,
    const unsigned int* __restrict__ packed, const int* __restrict__ labels,
    float* __restrict__ tot, float* __restrict__ msk)
{
  __shared__ unsigned char lds[TB * LDS_COL];   // 34.8 KB
  int tid = threadIdx.x;
  int wave = tid >> 6, lane = tid & 63;
  int q = lane >> 4, c = lane & 15;
  int wm = wave >> 1, wn = wave & 1;

  // decode blockIdx -> (ri, cj), ri <= cj, row-major over the upper triangle
  int bid = blockIdx.x;
  int ri = (int)((129.0f - sqrtf(129.0f * 129.0f - 8.0f * (float)bid)) * 0.5f);
  while (ri * (129 - ri) / 2 > bid) ri--;
  while ((ri + 1) * (128 - ri) / 2 <= bid) ri++;
  int cj = ri + (bid - ri * (129 - ri) / 2);
  int rblock = ri * TB, colbase = cj * TB;

  // ---- issue B-tile staging loads (128 rows of xnB = this tile's cols) ----
  int scol = tid & 127, sh8 = (tid >> 7) * 8;   // 2 threads/col, 8 uint4 each
  const uint4* gsrc = (const uint4*)((const char*)xnB_u + (size_t)(colbase + scol) * 256) + sh8;
  uint4 stg[8];
  #pragma unroll
  for (int u = 0; u < 8; u++) stg[u] = gsrc[u];

  // ---- A fragments: 4 strips x 4 K-frags (rows rblock + wm*64 + st*16 + c) ----
  const bf16x8* xnvA = (const bf16x8*)xnA_u;
  bf16x8 a[4][4];
  #pragma unroll
  for (int st = 0; st < 4; st++) {
    const bf16x8* ap = xnvA + (size_t)(rblock + wm * 64 + st * 16 + c) * (DD / 8) + q;
    a[st][0] = ap[0]; a[st][1] = ap[4]; a[st][2] = ap[8]; a[st][3] = ap[12];
  }

  // ---- row-side mask words: bit(label_i, j) for j in this wave's 64 cols ----
  int q4 = q * 4;
  int cw0 = (colbase >> 5) + wn * 2;
  unsigned wrow[2][4][4];   // [colword p][strip][k]
  #pragma unroll
  for (int st = 0; st < 4; st++) {
    #pragma unroll
    for (int k = 0; k < 4; k++) {
      unsigned off = (unsigned)labels[rblock + wm * 64 + st * 16 + q4 + k] * 256u + cw0;
      wrow[0][st][k] = packed[off];
      wrow[1][st][k] = packed[off + 1];
    }
  }
  // ---- col-side mask words: bit(label_j, i) for i in this wave's 64 rows ----
  int rw0 = (rblock >> 5) + wm * 2;
  unsigned cwv[4][2];       // [colgroup g][rows 0-31 / 32-63]
  #pragma unroll
  for (int g = 0; g < 4; g++) {
    unsigned off = (unsigned)labels[colbase + wn * 64 + g * 16 + c] * 256u + rw0;
    cwv[g][0] = packed[off];
    cwv[g][1] = packed[off + 1];
  }

  // ---- write staged B to LDS, single barrier ----
  {
    uint4* dst = (uint4*)(lds + (unsigned)(scol * LDS_COL) + sh8 * 16);
    #pragma unroll
    for (int u = 0; u < 8; u++) dst[u] = stg[u];
  }
  __syncthreads();

  float tacc[4][4], macc[4][4], tcol[4], mcol[4];
  #pragma unroll
  for (int st = 0; st < 4; st++)
    #pragma unroll
    for (int k = 0; k < 4; k++) { tacc[st][k] = 0.f; macc[st][k] = 0.f; }
  #pragma unroll
  for (int g = 0; g < 4; g++) { tcol[g] = 0.f; mcol[g] = 0.f; }

  int posr0 = c, posr1 = c + 16;

  #pragma unroll
  for (int g = 0; g < 4; g++) {
    const bf16x8* bl = (const bf16x8*)(lds + (unsigned)((wn * 64 + g * 16 + c) * LDS_COL) + q * 16);
    bf16x8 b0 = bl[0], b1 = bl[4], b2 = bl[8], b3 = bl[12];

    f32x4 acc[4];
    #pragma unroll
    for (int st = 0; st < 4; st++) acc[st] = (f32x4){0, 0, 0, 0};
    #pragma unroll
    for (int st = 0; st < 4; st++)
      acc[st] = __builtin_amdgcn_mfma_f32_16x16x32_bf16(a[st][0], b0, acc[st], 0, 0, 0);
    #pragma unroll
    for (int st = 0; st < 4; st++)
      acc[st] = __builtin_amdgcn_mfma_f32_16x16x32_bf16(a[st][1], b1, acc[st], 0, 0, 0);
    #pragma unroll
    for (int st = 0; st < 4; st++)
      acc[st] = __builtin_amdgcn_mfma_f32_16x16x32_bf16(a[st][2], b2, acc[st], 0, 0, 0);
    #pragma unroll
    for (int st = 0; st < 4; st++)
      acc[st] = __builtin_amdgcn_mfma_f32_16x16x32_bf16(a[st][3], b3, acc[st], 0, 0, 0);

    // pre-shift col-mask words so the per-element bit index is compile-const
    unsigned cwqA = cwv[g][0] >> q4;   // strips 0,1 (rows 0-31 of wave)
    unsigned cwqB = cwv[g][1] >> q4;   // strips 2,3 (rows 32-63)
    int posr = (g & 1) ? posr1 : posr0;

    #pragma unroll
    for (int st = 0; st < 4; st++) {
      unsigned cwq = (st < 2) ? cwqA : cwqB;
      #pragma unroll
      for (int k = 0; k < 4; k++) {
        float e = __builtin_amdgcn_exp2f(acc[st][k]);
        // row contribution (row = rblock + wm*64 + st*16 + q*4+k, col bit posr)
        tacc[st][k] += e;
        int smr;
        asm("v_bfe_i32 %0, %1, %2, 1" : "=v"(smr) : "v"(wrow[g >> 1][st][k]), "v"(posr));
        union { float f; int i; } ur; ur.f = e; ur.i &= smr;
        macc[st][k] += ur.f;
        // col contribution (col = colbase + wn*64 + g*16 + c, row bit posc)
        tcol[g] += e;
        int posc = (st & 1) * 16 + k;
        int smc;
        asm("v_bfe_i32 %0, %1, %2, 1" : "=v"(smc) : "v"(cwq), "v"(posc));
        union { float f; int i; } uc; uc.f = e; uc.i &= smc;
        mcol[g] += uc.f;
      }
    }
  }

  // ---- row sums: reduce over the 16 c-lanes, atomically add ----
  #pragma unroll
  for (int sh = 1; sh < 16; sh <<= 1) {
    #pragma unroll
    for (int st = 0; st < 4; st++) {
      #pragma unroll
      for (int k = 0; k < 4; k++) {
        tacc[st][k] += __shfl_xor(tacc[st][k], sh);
        macc[st][k] += __shfl_xor(macc[st][k], sh);
      }
    }
  }
  if (c == 0) {
    #pragma unroll
    for (int st = 0; st < 4; st++) {
      #pragma unroll
      for (int k = 0; k < 4; k++) {
        int r = rblock + wm * 64 + st * 16 + q4 + k;
        atomicAdd(&tot[r], tacc[st][k]);
        atomicAdd(&msk[r], macc[st][k]);
      }
    }
  }

  // ---- col sums: reduce over the 4 q-groups, atomically add (off-diag only) ----
  #pragma unroll
  for (int g = 0; g < 4; g++) {
    tcol[g] += __shfl_xor(tcol[g], 16); tcol[g] += __shfl_xor(tcol[g], 32);
    mcol[g] += __shfl_xor(mcol[g], 16); mcol[g] += __shfl_xor(mcol[g], 32);
  }
  if (ri != cj && q == 0) {
    #pragma unroll
    for (int g = 0; g < 4; g++) {
      int j = colbase + wn * 64 + g * 16 + c;
      atomicAdd(&tot[j], tcol[g]);
      atomicAdd(&msk[j], mcol[g]);
    }
  }
}

// Kernel 3: loss = mean(log(p+tot') - log(p+msk')), diagonal subtracted here.
__global__ __launch_bounds__(256) void loss_kernel(
    const float* __restrict__ p, const float* __restrict__ tot,
    const float* __restrict__ msk, const float* __restrict__ eself,
    const float* __restrict__ mii, float* __restrict__ out)
{
  __shared__ float sd[4];
  int r = blockIdx.x * 256 + threadIdx.x;
  float pi = p[r];
  float es = eself[r];
  float t = tot[r] - es;                 // remove diagonal from total sum
  float m = msk[r] - es * mii[r];        // remove diagonal from masked sum
  float v = __builtin_amdgcn_logf(pi + t) - __builtin_amdgcn_logf(pi + m);
  float s = v * (1.0f / (LOG2E * (float)NROWS));
  #pragma unroll
  for (int sh = 1; sh < 64; sh <<= 1) s += __shfl_xor(s, sh);
  int wave = threadIdx.x >> 6, lane = threadIdx.x & 63;
  if (lane == 0) sd[wave] = s;
  __syncthreads();
  if (threadIdx.x == 0) atomicAdd(out, sd[0] + sd[1] + sd[2] + sd[3]);
}

extern "C" void kernel_launch(void* const* d_in, const int* in_sizes, int n_in,
                              void* d_out, int out_size, void* d_ws, size_t ws_size,
                              hipStream_t stream) {
  const float* x  = (const float*)d_in[0];   // inst_embed [N,D]
  const float* pr = (const float*)d_in[1];   // proxy [N,D]
  const float* nm = (const float*)d_in[2];   // negative_mask [100,N]
  const int*   lb = (const int*)d_in[3];     // labels [N]
  const float* tp = (const float*)d_in[4];   // temperature
  // margin (d_in[5]) cancels algebraically in numerator/denominator

  char* ws = (char*)d_ws;
  unsigned short* xnA = (unsigned short*)ws;                        // 2 MB
  unsigned short* xnB = xnA + (size_t)NROWS * DD;                   // 2 MB
  float* p     = (float*)(xnB + (size_t)NROWS * DD);
  float* tot   = p + NROWS;
  float* msk   = tot + NROWS;
  float* eself = msk + NROWS;
  float* miiv  = eself + NROWS;
  unsigned int* packed = (unsigned int*)(miiv + NROWS);             // 102.4 KB
  float* out = (float*)d_out;

  norm_kernel<<<NORM_BLOCKS + PACK_BLOCKS, 256, 0, stream>>>(
      x, pr, nm, lb, tp, xnA, xnB, p, eself, miiv, tot, msk, packed, out);
  main_kernel<<<NPAIRS, 256, 0, stream>>>(xnA, xnB, packed, lb, tot, msk);
  loss_kernel<<<NROWS / 256, 256, 0, stream>>>(p, tot, msk, eself, miiv, out);
}

// Round 3
// 144.955 us; speedup vs baseline: 1.0697x; 1.0697x over previous
//
#include <hip/hip_runtime.h>
#include <stdint.h>

#define NROWS 8192
#define DD 128
#define EPS 1e-8f
#define LOG2E 1.4426950408889634f

// triangle-pipelined main kernel tiling
#define SPLITQ 32                      // column chunks
#define CPW 256                        // cols per chunk (NROWS/SPLITQ)
#define CPT 32                         // cols per LDS tile
#define NT (CPW / CPT)                 // 8 tiles per chunk
#define NBLK (SPLITQ * (SPLITQ + 1))   // 1056 kept (strip,chunk) pairs, by >= bx/2
#define LDS_COL 272    // bytes per staged col (256+16 pad)
#define NORM_BLOCKS (NROWS / 4)
#define PACK_BLOCKS 3200   // 100 classes * 128 u64-words / 4 waves

typedef __bf16 bf16x8 __attribute__((ext_vector_type(8)));
typedef float f32x4 __attribute__((ext_vector_type(4)));

__device__ __forceinline__ unsigned int f2bf(float f) {
  union { float f; unsigned int u; } v; v.f = f;
  unsigned int u = v.u;
  return (u + 0x7fffu + ((u >> 16) & 1u)) >> 16;
}
__device__ __forceinline__ float bf2f(unsigned int b) {
  union { unsigned int u; float f; } v; v.u = b << 16;
  return v.f;
}

// Kernel 1 (blocks < NORM_BLOCKS): per-row normalize.
//   xnA = bf16(x/||x|| * log2e/T)  (A operand pre-scaled: e = exp2(acc))
//   xnB = bf16(x/||x||)            (B operand)
//   p = exp2(cos(x,proxy)*log2e/T)  [margin cancels in num/den ratio]
//   e_self = exp2(<xnA_bf16, xnB_bf16>)  (MFMA diagonal, subtracted in loss)
//   mii = negmask[label_i][i]; zero tot/msk/out.
// Kernel 1 (blocks >= NORM_BLOCKS): ballot-pack negmask into u32 bit-words:
//   packed[class*256 + j/32] bit (j&31) = (negmask[class][j] != 0)
__global__ __launch_bounds__(256) void norm_kernel(
    const float* __restrict__ x, const float* __restrict__ pr,
    const float* __restrict__ nm, const int* __restrict__ lb,
    const float* __restrict__ tptr,
    unsigned short* __restrict__ xnA, unsigned short* __restrict__ xnB,
    float* __restrict__ p, float* __restrict__ eself, float* __restrict__ mii,
    float* __restrict__ tot, float* __restrict__ msk,
    unsigned int* __restrict__ packed, float* __restrict__ out)
{
  int wave = threadIdx.x >> 6, lane = threadIdx.x & 63;
  int bx = blockIdx.x;

  if (bx >= NORM_BLOCKS) {
    // ---- mask pack branch ----
    int widx = (bx - NORM_BLOCKS) * 4 + wave;   // 0..12799
    int cls = widx >> 7;                        // 0..99
    int w64 = widx & 127;                       // u64-word within class
    float v = nm[(size_t)cls * NROWS + w64 * 64 + lane];
    unsigned long long b = __ballot(v != 0.0f);
    if (lane == 0) {
      packed[cls * 256 + w64 * 2] = (unsigned int)b;
      packed[cls * 256 + w64 * 2 + 1] = (unsigned int)(b >> 32);
    }
    return;
  }

  int row = bx * 4 + wave;
  float2 xv = ((const float2*)(x + (size_t)row * DD))[lane];
  float2 pv = ((const float2*)(pr + (size_t)row * DD))[lane];
  float sx = xv.x * xv.x + xv.y * xv.y;
  float sp = pv.x * pv.x + pv.y * pv.y;
  float dp = xv.x * pv.x + xv.y * pv.y;
  #pragma unroll
  for (int m = 1; m < 64; m <<= 1) {
    sx += __shfl_xor(sx, m);
    sp += __shfl_xor(sp, m);
    dp += __shfl_xor(dp, m);
  }
  float inx = 1.f / fmaxf(sqrtf(sx), EPS);
  float inp = 1.f / fmaxf(sqrtf(sp), EPS);
  float s1 = LOG2E / tptr[0];

  unsigned int a0 = f2bf(xv.x * inx * s1), a1 = f2bf(xv.y * inx * s1);
  unsigned int b0 = f2bf(xv.x * inx),      b1 = f2bf(xv.y * inx);
  ((unsigned int*)(xnA + (size_t)row * DD))[lane] = a0 | (a1 << 16);
  ((unsigned int*)(xnB + (size_t)row * DD))[lane] = b0 | (b1 << 16);

  // self-sim with the SAME rounded values the MFMA will see
  float ss = bf2f(a0) * bf2f(b0) + bf2f(a1) * bf2f(b1);
  #pragma unroll
  for (int m = 1; m < 64; m <<= 1) ss += __shfl_xor(ss, m);

  if (lane == 0) {
    p[row] = __builtin_amdgcn_exp2f(dp * inx * inp * s1);
    eself[row] = __builtin_amdgcn_exp2f(ss);
    mii[row] = nm[(size_t)lb[row] * NROWS + row];
    tot[row] = 0.f;
    msk[row] = 0.f;
    if (row == 0) out[0] = 0.f;
  }
}

// Kernel 2 (triangle + R0 pipeline): block = (row strip bx of 128) x (col
// chunk by of 256), kept only for by >= bx/2 (upper triangle). e_ij = e_ji:
// each off-diagonal tile adds row-sums (rows of strip) AND col-sums (rows =
// cols of chunk, via LDS accumulators + one global flush). The 128x128
// diagonal block is computed fully with row-sums only. Pipeline identical to
// the proven R0 kernel: 8 tiles of 32 cols, double-buffered LDS, coalesced
// staging (16 threads/col-row), one barrier per tile, prefetch of B tile +
// row-mask words + col-label/mask words during compute.
__global__ __launch_bounds__(256, 4) void main_kernel(
    const unsigned short* __restrict__ xnA_u, const unsigned short* __restrict__ xnB_u,
    const unsigned int* __restrict__ packed, const int* __restrict__ labels,
    float* __restrict__ tot, float* __restrict__ msk)
{
  __shared__ unsigned char lds[2][CPT * LDS_COL];   // 2 x 8704 B
  __shared__ float colacc[2][CPW];                  // col-sum accumulators (2 KB)
  int tid = threadIdx.x;
  int wave = tid >> 6, lane = tid & 63;
  int q = lane >> 4, c = lane & 15;

  // decode flat block id -> (bx, by) with by >= bx/2; count(by) = 2by+2,
  // cum(by) = by*(by+1)
  int n = blockIdx.x;
  int by = (int)((sqrtf((float)(4 * n + 1)) - 1.0f) * 0.5f);
  while (by * (by + 1) > n) by--;
  while ((by + 1) * (by + 2) <= n) by++;
  int bx = n - by * (by + 1);

  int rblock = bx * 128;
  int jb = by * CPW;
  int diag = (by == (bx >> 1));
  int tstart = diag ? 4 * (bx & 1) : 0;   // skip tiles fully below diagonal
  int tcol0  = diag ? tstart + 4 : 0;     // first col-eligible tile

  int rb0 = rblock + wave * 16;  // strip 0 row base
  int rb1 = rb0 + 64;            // strip 1 row base

  const bf16x8* xnvA = (const bf16x8*)xnA_u;

  // A fragments (held in registers for the whole column loop)
  bf16x8 a0[4], a1[4];
  {
    const bf16x8* b = xnvA + (size_t)(rb0 + c) * (DD / 8) + q;
    a0[0] = b[0]; a0[1] = b[4]; a0[2] = b[8]; a0[3] = b[12];
  }
  {
    const bf16x8* b = xnvA + (size_t)(rb1 + c) * (DD / 8) + q;
    a1[0] = b[0]; a1[1] = b[4]; a1[2] = b[8]; a1[3] = b[12];
  }

  // zero col accumulators (covered by the staging barrier below)
  ((float*)colacc)[tid] = 0.f;
  ((float*)colacc)[tid + 256] = 0.f;

  // Epilogue rows for this lane: row_local = q*4 + k, col = s*16 + c
  int q4 = q * 4;
  int r0[4], r1[4];
  unsigned int offP0[4], offP1[4];        // packed row-mask word offsets
  #pragma unroll
  for (int k = 0; k < 4; k++) {
    r0[k] = rb0 + q4 + k;
    r1[k] = rb1 + q4 + k;
    offP0[k] = (unsigned int)labels[r0[k]] * 256u + (unsigned int)(jb >> 5);
    offP1[k] = (unsigned int)labels[r1[k]] * 256u + (unsigned int)(jb >> 5);
  }
  float t0[4] = {0, 0, 0, 0}, m0[4] = {0, 0, 0, 0};
  float t1[4] = {0, 0, 0, 0}, m1[4] = {0, 0, 0, 0};

  // staging: thread t loads/writes 2x 16B: cols scol, scol+16, chunk schunk
  int scol = tid >> 4, schunk = tid & 15;
  const char* gB = (const char*)xnB_u;
  const char* gbase = gB + (size_t)(jb + scol) * 256 + schunk * 16;
  unsigned int ldsoff = (unsigned int)(scol * LDS_COL + schunk * 16);

  unsigned int rw = (unsigned int)(rblock >> 5);   // row-word base for col masks
  unsigned int wsel = (unsigned int)(wave >> 1);   // which 32-row word this wave's rows sit in
  int base01 = (wave & 1) * 16 + q4;               // bit base within that word

  // prefetch + stage tile tstart into its buffer
  uint4 g0 = *(const uint4*)(gbase + (size_t)tstart * (CPT * 256));
  uint4 g1 = *(const uint4*)(gbase + (size_t)tstart * (CPT * 256) + 16 * 256);
  unsigned int wn0[4], wn1[4];
  #pragma unroll
  for (int k = 0; k < 4; k++) {
    wn0[k] = packed[offP0[k] + tstart];
    wn1[k] = packed[offP1[k] + tstart];
  }
  unsigned int ncw[4] = {0, 0, 0, 0};
  if (tstart >= tcol0) {   // only full blocks (tstart=0, tcol0=0)
    unsigned int lab0 = (unsigned int)labels[jb + tstart * 32 + c];
    unsigned int lab1 = (unsigned int)labels[jb + tstart * 32 + 16 + c];
    ncw[0] = packed[lab0 * 256u + rw + wsel];
    ncw[1] = packed[lab0 * 256u + rw + 2u + wsel];
    ncw[2] = packed[lab1 * 256u + rw + wsel];
    ncw[3] = packed[lab1 * 256u + rw + 2u + wsel];
  }
  *(uint4*)(lds[tstart & 1] + ldsoff)                = g0;
  *(uint4*)(lds[tstart & 1] + ldsoff + 16 * LDS_COL) = g1;
  __syncthreads();

  for (int t = tstart; t < NT; t++) {
    unsigned int wc0[4], wc1[4], ccw[4];
    #pragma unroll
    for (int k = 0; k < 4; k++) { wc0[k] = wn0[k]; wc1[k] = wn1[k]; }
    #pragma unroll
    for (int k = 0; k < 4; k++) ccw[k] = ncw[k];
    int docol = (t >= tcol0);

    // issue tile t+1 loads (land during this tile's compute)
    if (t + 1 < NT) {
      const char* gb = gbase + (size_t)(t + 1) * (CPT * 256);
      g0 = *(const uint4*)(gb);
      g1 = *(const uint4*)(gb + 16 * 256);
      #pragma unroll
      for (int k = 0; k < 4; k++) {
        wn0[k] = packed[offP0[k] + t + 1];
        wn1[k] = packed[offP1[k] + t + 1];
      }
      if (t + 1 >= tcol0) {
        unsigned int lab0 = (unsigned int)labels[jb + (t + 1) * 32 + c];
        unsigned int lab1 = (unsigned int)labels[jb + (t + 1) * 32 + 16 + c];
        ncw[0] = packed[lab0 * 256u + rw + wsel];
        ncw[1] = packed[lab0 * 256u + rw + 2u + wsel];
        ncw[2] = packed[lab1 * 256u + rw + wsel];
        ncw[3] = packed[lab1 * 256u + rw + 2u + wsel];
      }
    }

    const unsigned char* buf = lds[t & 1];
    #pragma unroll
    for (int s = 0; s < 2; s++) {
      const bf16x8* bl = (const bf16x8*)(buf + (unsigned)(s * 16 + c) * LDS_COL + q * 16);
      bf16x8 b0 = bl[0], b1 = bl[4], b2 = bl[8], b3 = bl[12];

      f32x4 acc0 = {0, 0, 0, 0};
      f32x4 acc1 = {0, 0, 0, 0};
      acc0 = __builtin_amdgcn_mfma_f32_16x16x32_bf16(a0[0], b0, acc0, 0, 0, 0);
      acc1 = __builtin_amdgcn_mfma_f32_16x16x32_bf16(a1[0], b0, acc1, 0, 0, 0);
      acc0 = __builtin_amdgcn_mfma_f32_16x16x32_bf16(a0[1], b1, acc0, 0, 0, 0);
      acc1 = __builtin_amdgcn_mfma_f32_16x16x32_bf16(a1[1], b1, acc1, 0, 0, 0);
      acc0 = __builtin_amdgcn_mfma_f32_16x16x32_bf16(a0[2], b2, acc0, 0, 0, 0);
      acc1 = __builtin_amdgcn_mfma_f32_16x16x32_bf16(a1[2], b2, acc1, 0, 0, 0);
      acc0 = __builtin_amdgcn_mfma_f32_16x16x32_bf16(a0[3], b3, acc0, 0, 0, 0);
      acc1 = __builtin_amdgcn_mfma_f32_16x16x32_bf16(a1[3], b3, acc1, 0, 0, 0);

      int pos = s * 16 + c;     // bit position in packed row-mask word
      unsigned int cwS0 = s ? ccw[2] : ccw[0];  // col-mask word, strip 0 rows
      unsigned int cwS1 = s ? ccw[3] : ccw[1];  // col-mask word, strip 1 rows
      float colT = 0.f, colM = 0.f;
      #pragma unroll
      for (int k = 0; k < 4; k++) {
        float e = __builtin_amdgcn_exp2f(acc0[k]);
        t0[k] += e;
        int smr;
        asm("v_bfe_i32 %0, %1, %2, 1" : "=v"(smr) : "v"(wc0[k]), "v"(pos));
        union { float f; int i; } ur; ur.f = e; ur.i &= smr;
        m0[k] += ur.f;
        if (docol) {
          colT += e;
          int pc = base01 + k;
          int smc;
          asm("v_bfe_i32 %0, %1, %2, 1" : "=v"(smc) : "v"(cwS0), "v"(pc));
          union { float f; int i; } uc; uc.f = e; uc.i &= smc;
          colM += uc.f;
        }
      }
      #pragma unroll
      for (int k = 0; k < 4; k++) {
        float e = __builtin_amdgcn_exp2f(acc1[k]);
        t1[k] += e;
        int smr;
        asm("v_bfe_i32 %0, %1, %2, 1" : "=v"(smr) : "v"(wc1[k]), "v"(pos));
        union { float f; int i; } ur; ur.f = e; ur.i &= smr;
        m1[k] += ur.f;
        if (docol) {
          colT += e;
          int pc = base01 + k;
          int smc;
          asm("v_bfe_i32 %0, %1, %2, 1" : "=v"(smc) : "v"(cwS1), "v"(pc));
          union { float f; int i; } uc; uc.f = e; uc.i &= smc;
          colM += uc.f;
        }
      }
      if (docol) {
        // reduce the 4 q-groups (cols identical across q): lanes 0-15 hold sums
        colT += __shfl_xor(colT, 16); colT += __shfl_xor(colT, 32);
        colM += __shfl_xor(colM, 16); colM += __shfl_xor(colM, 32);
        if (q == 0) {
          atomicAdd(&colacc[0][t * 32 + pos], colT);
          atomicAdd(&colacc[1][t * 32 + pos], colM);
        }
      }
    }

    // stage tile t+1 into the other buffer (waits on prefetch), one barrier
    if (t + 1 < NT) {
      unsigned char* nb = (unsigned char*)lds[(t + 1) & 1];
      *(uint4*)(nb + ldsoff)                = g0;
      *(uint4*)(nb + ldsoff + 16 * LDS_COL) = g1;
    }
    __syncthreads();
  }

  // Row sums: reduce across the 16 lanes (c) sharing each q group.
  #pragma unroll
  for (int sh = 1; sh < 16; sh <<= 1) {
    #pragma unroll
    for (int k = 0; k < 4; k++) {
      t0[k] += __shfl_xor(t0[k], sh);
      m0[k] += __shfl_xor(m0[k], sh);
      t1[k] += __shfl_xor(t1[k], sh);
      m1[k] += __shfl_xor(m1[k], sh);
    }
  }
  if (c == 0) {
    #pragma unroll
    for (int k = 0; k < 4; k++) {
      atomicAdd(&tot[r0[k]], t0[k]);
      atomicAdd(&msk[r0[k]], m0[k]);
      atomicAdd(&tot[r1[k]], t1[k]);
      atomicAdd(&msk[r1[k]], m1[k]);
    }
  }

  // Col sums: one cooperative flush per block (last __syncthreads of the
  // t-loop guarantees all LDS atomics have landed).
  int ci = tid;   // 0..255 = one col of this chunk
  if (ci >= tcol0 * 32) {
    atomicAdd(&tot[jb + ci], colacc[0][ci]);
    atomicAdd(&msk[jb + ci], colacc[1][ci]);
  }
}

// Kernel 3: loss = mean(log(p+tot') - log(p+msk')), diagonal subtracted here.
__global__ __launch_bounds__(256) void loss_kernel(
    const float* __restrict__ p, const float* __restrict__ tot,
    const float* __restrict__ msk, const float* __restrict__ eself,
    const float* __restrict__ mii, float* __restrict__ out)
{
  __shared__ float sd[4];
  int r = blockIdx.x * 256 + threadIdx.x;
  float pi = p[r];
  float es = eself[r];
  float t = tot[r] - es;                 // remove diagonal from total sum
  float m = msk[r] - es * mii[r];        // remove diagonal from masked sum
  float v = __builtin_amdgcn_logf(pi + t) - __builtin_amdgcn_logf(pi + m);
  float s = v * (1.0f / (LOG2E * (float)NROWS));
  #pragma unroll
  for (int sh = 1; sh < 64; sh <<= 1) s += __shfl_xor(s, sh);
  int wave = threadIdx.x >> 6, lane = threadIdx.x & 63;
  if (lane == 0) sd[wave] = s;
  __syncthreads();
  if (threadIdx.x == 0) atomicAdd(out, sd[0] + sd[1] + sd[2] + sd[3]);
}

extern "C" void kernel_launch(void* const* d_in, const int* in_sizes, int n_in,
                              void* d_out, int out_size, void* d_ws, size_t ws_size,
                              hipStream_t stream) {
  const float* x  = (const float*)d_in[0];   // inst_embed [N,D]
  const float* pr = (const float*)d_in[1];   // proxy [N,D]
  const float* nm = (const float*)d_in[2];   // negative_mask [100,N]
  const int*   lb = (const int*)d_in[3];     // labels [N]
  const float* tp = (const float*)d_in[4];   // temperature
  // margin (d_in[5]) cancels algebraically in numerator/denominator

  char* ws = (char*)d_ws;
  unsigned short* xnA = (unsigned short*)ws;                        // 2 MB
  unsigned short* xnB = xnA + (size_t)NROWS * DD;                   // 2 MB
  float* p     = (float*)(xnB + (size_t)NROWS * DD);
  float* tot   = p + NROWS;
  float* msk   = tot + NROWS;
  float* eself = msk + NROWS;
  float* miiv  = eself + NROWS;
  unsigned int* packed = (unsigned int*)(miiv + NROWS);             // 102.4 KB
  float* out = (float*)d_out;

  norm_kernel<<<NORM_BLOCKS + PACK_BLOCKS, 256, 0, stream>>>(
      x, pr, nm, lb, tp, xnA, xnB, p, eself, miiv, tot, msk, packed, out);
  main_kernel<<<NBLK, 256, 0, stream>>>(xnA, xnB, packed, lb, tot, msk);
  loss_kernel<<<NROWS / 256, 256, 0, stream>>>(p, tot, msk, eself, miiv, out);
}

// Round 4
// 109.080 us; speedup vs baseline: 1.4216x; 1.3289x over previous
//
#include <hip/hip_runtime.h>
#include <stdint.h>

#define NROWS 8192
#define DD 128
#define EPS 1e-8f
#define LOG2E 1.4426950408889634f

// main kernel tiling (R0 skeleton + async triple-buffer staging)
#define SPLIT 16       // column splits (blocks cooperating per row-strip)
#define RPB 128        // rows per block (4 waves x 2 strips x 16 rows)
#define CPT 32         // cols per LDS tile
#define TILEB (CPT * 256)            // 8192 B per buffer (linear, no pad)
#define NT ((NROWS / SPLIT) / CPT)   // 16 tiles per block
#define NORM_BLOCKS (NROWS / 4)
#define PACK_BLOCKS 3200   // 100 classes * 128 u64-words / 4 waves

typedef __bf16 bf16x8 __attribute__((ext_vector_type(8)));
typedef float f32x4 __attribute__((ext_vector_type(4)));

__device__ __forceinline__ unsigned int f2bf(float f) {
  union { float f; unsigned int u; } v; v.f = f;
  unsigned int u = v.u;
  return (u + 0x7fffu + ((u >> 16) & 1u)) >> 16;
}
__device__ __forceinline__ float bf2f(unsigned int b) {
  union { unsigned int u; float f; } v; v.u = b << 16;
  return v.f;
}

// async 16B global -> LDS (dest = wave-uniform base + lane*16)
__device__ __forceinline__ void gl16(const void* g, void* l) {
  __builtin_amdgcn_global_load_lds(
      (const __attribute__((address_space(1))) unsigned int*)g,
      (__attribute__((address_space(3))) unsigned int*)l, 16, 0, 0);
}

// Kernel 1 (blocks < NORM_BLOCKS): per-row normalize.
//   xnA = bf16(x/||x|| * log2e/T)  (A operand pre-scaled: e = exp2(acc))
//   xnB = bf16(x/||x||)            (B operand)
//   p = exp2(cos(x,proxy)*log2e/T)  [margin cancels in num/den ratio]
//   e_self = exp2(<xnA_bf16, xnB_bf16>)  (MFMA diagonal, subtracted in loss)
//   mii = negmask[label_i][i]; zero tot/msk/out.
// Kernel 1 (blocks >= NORM_BLOCKS): ballot-pack negmask into u32 bit-words:
//   packed[class*256 + j/32] bit (j&31) = (negmask[class][j] != 0)
__global__ __launch_bounds__(256) void norm_kernel(
    const float* __restrict__ x, const float* __restrict__ pr,
    const float* __restrict__ nm, const int* __restrict__ lb,
    const float* __restrict__ tptr,
    unsigned short* __restrict__ xnA, unsigned short* __restrict__ xnB,
    float* __restrict__ p, float* __restrict__ eself, float* __restrict__ mii,
    float* __restrict__ tot, float* __restrict__ msk,
    unsigned int* __restrict__ packed, float* __restrict__ out)
{
  int wave = threadIdx.x >> 6, lane = threadIdx.x & 63;
  int bx = blockIdx.x;

  if (bx >= NORM_BLOCKS) {
    // ---- mask pack branch ----
    int widx = (bx - NORM_BLOCKS) * 4 + wave;   // 0..12799
    int cls = widx >> 7;                        // 0..99
    int w64 = widx & 127;                       // u64-word within class
    float v = nm[(size_t)cls * NROWS + w64 * 64 + lane];
    unsigned long long b = __ballot(v != 0.0f);
    if (lane == 0) {
      packed[cls * 256 + w64 * 2] = (unsigned int)b;
      packed[cls * 256 + w64 * 2 + 1] = (unsigned int)(b >> 32);
    }
    return;
  }

  int row = bx * 4 + wave;
  float2 xv = ((const float2*)(x + (size_t)row * DD))[lane];
  float2 pv = ((const float2*)(pr + (size_t)row * DD))[lane];
  float sx = xv.x * xv.x + xv.y * xv.y;
  float sp = pv.x * pv.x + pv.y * pv.y;
  float dp = xv.x * pv.x + xv.y * pv.y;
  #pragma unroll
  for (int m = 1; m < 64; m <<= 1) {
    sx += __shfl_xor(sx, m);
    sp += __shfl_xor(sp, m);
    dp += __shfl_xor(dp, m);
  }
  float inx = 1.f / fmaxf(sqrtf(sx), EPS);
  float inp = 1.f / fmaxf(sqrtf(sp), EPS);
  float s1 = LOG2E / tptr[0];

  unsigned int a0 = f2bf(xv.x * inx * s1), a1 = f2bf(xv.y * inx * s1);
  unsigned int b0 = f2bf(xv.x * inx),      b1 = f2bf(xv.y * inx);
  ((unsigned int*)(xnA + (size_t)row * DD))[lane] = a0 | (a1 << 16);
  ((unsigned int*)(xnB + (size_t)row * DD))[lane] = b0 | (b1 << 16);

  // self-sim with the SAME rounded values the MFMA will see
  float ss = bf2f(a0) * bf2f(b0) + bf2f(a1) * bf2f(b1);
  #pragma unroll
  for (int m = 1; m < 64; m <<= 1) ss += __shfl_xor(ss, m);

  if (lane == 0) {
    p[row] = __builtin_amdgcn_exp2f(dp * inx * inp * s1);
    eself[row] = __builtin_amdgcn_exp2f(ss);
    mii[row] = nm[(size_t)lb[row] * NROWS + row];
    tot[row] = 0.f;
    msk[row] = 0.f;
    if (row == 0) out[0] = 0.f;
  }
}

// Kernel 2: fused sim-GEMM + exp + masked/total row-sum accumulation.
// R0 skeleton (RPB=128, 4 waves, 16 tiles of 32 cols) with async staging:
//   - TRIPLE-buffered LDS, stage 2 tiles ahead via global_load_lds (16B),
//     so ~1300cy of compute covers the ~900cy HBM latency.
//   - counted s_waitcnt vmcnt(2) + raw s_barrier per tile: the in-flight
//     t+2 loads are never drained in the loop (T4 pattern).
//   - gload_lds needs a LINEAR dest, so bank conflicts are handled by an
//     XOR chunk swizzle (chunk ^= col&7) applied to the global SOURCE addr
//     and the ds_read side (both-sides rule): 2-way max = free.
//   - sched_barrier(0) pins the gload issues as the last VMEM before each
//     counted vmcnt (no other vmem may sink past them).
__global__ __launch_bounds__(256, 4) void main_kernel(
    const unsigned short* __restrict__ xnA_u, const unsigned short* __restrict__ xnB_u,
    const unsigned int* __restrict__ packed, const int* __restrict__ labels,
    float* __restrict__ tot, float* __restrict__ msk)
{
  __shared__ unsigned char lds[3][TILEB];   // 3 x 8192 B
  int tid = threadIdx.x;
  int wave = tid >> 6, lane = tid & 63;
  int q = lane >> 4, c = lane & 15;
  int rb0 = blockIdx.x * RPB + wave * 16;  // strip 0 row base
  int rb1 = rb0 + 64;                      // strip 1 row base

  const bf16x8* xnvA = (const bf16x8*)xnA_u;

  // A fragments (held in registers for the whole column loop)
  // layout: m = lane&15, k = (lane>>4)*8 + j  per 32-wide K step
  bf16x8 a0[4], a1[4];
  {
    const bf16x8* b = xnvA + (size_t)(rb0 + c) * (DD / 8) + q;
    a0[0] = b[0]; a0[1] = b[4]; a0[2] = b[8]; a0[3] = b[12];
  }
  {
    const bf16x8* b = xnvA + (size_t)(rb1 + c) * (DD / 8) + q;
    a1[0] = b[0]; a1[1] = b[4]; a1[2] = b[8]; a1[3] = b[12];
  }

  int jb = blockIdx.y * (NROWS / SPLIT);

  // Epilogue rows for this lane: row_local = q*4 + k, col = s*16 + c
  int q4 = q * 4;
  int r0[4], r1[4];
  unsigned int offP0[4], offP1[4];        // packed-mask word offsets
  #pragma unroll
  for (int k = 0; k < 4; k++) {
    r0[k] = rb0 + q4 + k;
    r1[k] = rb1 + q4 + k;
    offP0[k] = (unsigned int)labels[r0[k]] * 256u + (unsigned int)(jb >> 5);
    offP1[k] = (unsigned int)labels[r1[k]] * 256u + (unsigned int)(jb >> 5);
  }
  float t0[4] = {0, 0, 0, 0}, m0[4] = {0, 0, 0, 0};
  float t1[4] = {0, 0, 0, 0}, m1[4] = {0, 0, 0, 0};

  // staging: thread t covers cols scol, scol+16 (chunk schunk), source
  // chunk pre-swizzled so the linear LDS image is the swizzled layout
  int scol = tid >> 4, schunk = tid & 15;
  int sx7 = scol & 7;                      // == (scol+16)&7
  const char* gB = (const char*)xnB_u;
  const char* gsrc = gB + (size_t)(jb + scol) * 256 + (schunk ^ sx7) * 16;
  // per-wave uniform LDS dest offsets (lane*16 is implicit in gload_lds)
  unsigned dof0 = (unsigned)(wave * 1024);
  unsigned dof1 = dof0 + 4096;

  // mask-word prefetch for tile 0
  unsigned int wn0[4], wn1[4];
  #pragma unroll
  for (int k = 0; k < 4; k++) {
    wn0[k] = packed[offP0[k]];
    wn1[k] = packed[offP1[k]];
  }

  // prologue: stage tiles 0,1 into buffers 0,1 (4 gloads in flight)
  gl16(gsrc,                     lds[0] + dof0);
  gl16(gsrc + 16 * 256,          lds[0] + dof1);
  gl16(gsrc + TILEB,             lds[1] + dof0);
  gl16(gsrc + TILEB + 16 * 256,  lds[1] + dof1);
  __builtin_amdgcn_sched_barrier(0);
  asm volatile("s_waitcnt vmcnt(2)" ::: "memory");   // tile 0 landed
  __builtin_amdgcn_sched_barrier(0);
  __builtin_amdgcn_s_barrier();

  unsigned cur = 0, nxt = 1, nx2 = 2;

  for (int t = 0; t < NT; t++) {
    unsigned int wc0[4], wc1[4];
    #pragma unroll
    for (int k = 0; k < 4; k++) { wc0[k] = wn0[k]; wc1[k] = wn1[k]; }

    // mask words for tile t+1 (clamped reload on last iter, in range)
    int tn = (t + 1 < NT) ? (t + 1) : (NT - 1);
    #pragma unroll
    for (int k = 0; k < 4; k++) {
      wn0[k] = packed[offP0[k] + tn];
      wn1[k] = packed[offP1[k] + tn];
    }

    // issue tile t+2 staging into the free buffer (dummy wrap at the tail —
    // lands in a buffer that is never read again)
    {
      int t2 = t + 2; if (t2 >= NT) t2 -= NT;
      const char* gs2 = gsrc + (size_t)t2 * TILEB;
      unsigned char* db = &lds[0][0] + nx2 * TILEB;
      gl16(gs2,            db + dof0);
      gl16(gs2 + 16 * 256, db + dof1);
    }
    __builtin_amdgcn_sched_barrier(0);   // gloads are the last VMEM issued

    const unsigned char* buf = &lds[0][0] + cur * TILEB;
    #pragma unroll
    for (int s = 0; s < 2; s++) {
      // swizzled read: col = s*16+c, chunk (q+4k) ^ (col&7)
      unsigned colb = (unsigned)((s * 16 + c) * 256);
      unsigned x7 = (unsigned)(c & 7);
      const unsigned char* bp = buf + colb;
      bf16x8 b0 = *(const bf16x8*)(bp + ((((unsigned)q)      ^ x7) << 4));
      bf16x8 b1 = *(const bf16x8*)(bp + ((((unsigned)q + 4)  ^ x7) << 4));
      bf16x8 b2 = *(const bf16x8*)(bp + ((((unsigned)q + 8)  ^ x7) << 4));
      bf16x8 b3 = *(const bf16x8*)(bp + ((((unsigned)q + 12) ^ x7) << 4));

      f32x4 acc0 = {0, 0, 0, 0};
      f32x4 acc1 = {0, 0, 0, 0};
      acc0 = __builtin_amdgcn_mfma_f32_16x16x32_bf16(a0[0], b0, acc0, 0, 0, 0);
      acc1 = __builtin_amdgcn_mfma_f32_16x16x32_bf16(a1[0], b0, acc1, 0, 0, 0);
      acc0 = __builtin_amdgcn_mfma_f32_16x16x32_bf16(a0[1], b1, acc0, 0, 0, 0);
      acc1 = __builtin_amdgcn_mfma_f32_16x16x32_bf16(a1[1], b1, acc1, 0, 0, 0);
      acc0 = __builtin_amdgcn_mfma_f32_16x16x32_bf16(a0[2], b2, acc0, 0, 0, 0);
      acc1 = __builtin_amdgcn_mfma_f32_16x16x32_bf16(a1[2], b2, acc1, 0, 0, 0);
      acc0 = __builtin_amdgcn_mfma_f32_16x16x32_bf16(a0[3], b3, acc0, 0, 0, 0);
      acc1 = __builtin_amdgcn_mfma_f32_16x16x32_bf16(a1[3], b3, acc1, 0, 0, 0);

      int pos = s * 16 + c;   // bit position in the packed u32 word
      #pragma unroll
      for (int k = 0; k < 4; k++) {
        float e = __builtin_amdgcn_exp2f(acc0[k]);
        t0[k] += e;
        int sm;   // sm = bit ? 0xFFFFFFFF : 0
        asm("v_bfe_i32 %0, %1, %2, 1" : "=v"(sm) : "v"(wc0[k]), "v"(pos));
        union { float f; int i; } u;
        u.f = e; u.i &= sm;
        m0[k] += u.f;
      }
      #pragma unroll
      for (int k = 0; k < 4; k++) {
        float e = __builtin_amdgcn_exp2f(acc1[k]);
        t1[k] += e;
        int sm;
        asm("v_bfe_i32 %0, %1, %2, 1" : "=v"(sm) : "v"(wc1[k]), "v"(pos));
        union { float f; int i; } u;
        u.f = e; u.i &= sm;
        m1[k] += u.f;
      }
    }

    // own t+1 loads drained (t+2 stay in flight), then meet the others
    asm volatile("s_waitcnt vmcnt(2)" ::: "memory");
    __builtin_amdgcn_sched_barrier(0);
    __builtin_amdgcn_s_barrier();

    unsigned tmp = cur; cur = nxt; nxt = nx2; nx2 = tmp;
  }

  // Reduce across the 16 lanes (c) sharing each q group.
  #pragma unroll
  for (int sh = 1; sh < 16; sh <<= 1) {
    #pragma unroll
    for (int k = 0; k < 4; k++) {
      t0[k] += __shfl_xor(t0[k], sh);
      m0[k] += __shfl_xor(m0[k], sh);
      t1[k] += __shfl_xor(t1[k], sh);
      m1[k] += __shfl_xor(m1[k], sh);
    }
  }
  if (c == 0) {
    #pragma unroll
    for (int k = 0; k < 4; k++) {
      atomicAdd(&tot[r0[k]], t0[k]);
      atomicAdd(&msk[r0[k]], m0[k]);
      atomicAdd(&tot[r1[k]], t1[k]);
      atomicAdd(&msk[r1[k]], m1[k]);
    }
  }
}

// Kernel 3: loss = mean(log(p+tot') - log(p+msk')), diagonal subtracted here.
__global__ __launch_bounds__(256) void loss_kernel(
    const float* __restrict__ p, const float* __restrict__ tot,
    const float* __restrict__ msk, const float* __restrict__ eself,
    const float* __restrict__ mii, float* __restrict__ out)
{
  __shared__ float sd[4];
  int r = blockIdx.x * 256 + threadIdx.x;
  float pi = p[r];
  float es = eself[r];
  float t = tot[r] - es;                 // remove diagonal from total sum
  float m = msk[r] - es * mii[r];        // remove diagonal from masked sum
  float v = __builtin_amdgcn_logf(pi + t) - __builtin_amdgcn_logf(pi + m);
  float s = v * (1.0f / (LOG2E * (float)NROWS));
  #pragma unroll
  for (int sh = 1; sh < 64; sh <<= 1) s += __shfl_xor(s, sh);
  int wave = threadIdx.x >> 6, lane = threadIdx.x & 63;
  if (lane == 0) sd[wave] = s;
  __syncthreads();
  if (threadIdx.x == 0) atomicAdd(out, sd[0] + sd[1] + sd[2] + sd[3]);
}

extern "C" void kernel_launch(void* const* d_in, const int* in_sizes, int n_in,
                              void* d_out, int out_size, void* d_ws, size_t ws_size,
                              hipStream_t stream) {
  const float* x  = (const float*)d_in[0];   // inst_embed [N,D]
  const float* pr = (const float*)d_in[1];   // proxy [N,D]
  const float* nm = (const float*)d_in[2];   // negative_mask [100,N]
  const int*   lb = (const int*)d_in[3];     // labels [N]
  const float* tp = (const float*)d_in[4];   // temperature
  // margin (d_in[5]) cancels algebraically in numerator/denominator

  char* ws = (char*)d_ws;
  unsigned short* xnA = (unsigned short*)ws;                        // 2 MB
  unsigned short* xnB = xnA + (size_t)NROWS * DD;                   // 2 MB
  float* p     = (float*)(xnB + (size_t)NROWS * DD);
  float* tot   = p + NROWS;
  float* msk   = tot + NROWS;
  float* eself = msk + NROWS;
  float* miiv  = eself + NROWS;
  unsigned int* packed = (unsigned int*)(miiv + NROWS);             // 102.4 KB
  float* out = (float*)d_out;

  norm_kernel<<<NORM_BLOCKS + PACK_BLOCKS, 256, 0, stream>>>(
      x, pr, nm, lb, tp, xnA, xnB, p, eself, miiv, tot, msk, packed, out);
  main_kernel<<<dim3(NROWS / RPB, SPLIT), 256, 0, stream>>>(xnA, xnB, packed,
                                                            lb, tot, msk);
  loss_kernel<<<NROWS / 256, 256, 0, stream>>>(p, tot, msk, eself, miiv, out);
}